// Round 4
// baseline (114.343 us; speedup 1.0000x reference)
//
#include <hip/hip_runtime.h>
#include <math.h>

#define T_N 100000
#define H_N 256
#define TM 32                  // tile rows
#define NT (T_N / TM)          // 3125 exact, no tail
#define GRID_AT 512

typedef __attribute__((ext_vector_type(8))) __bf16 bf16x8;
typedef __attribute__((ext_vector_type(4))) __bf16 bf16x4;
typedef __attribute__((ext_vector_type(4))) float f32x4;

// ws layout (bytes):
//       0 : WmT bf16 [256][256]   (131072)
//  131072 : proj f32 [256]        (1024)
//  132096 : At   f32 [100000]     (400000)
//  532096 : part2 float2[512]     (4096)
//  536192 : s1g  f32[256]         (1024)
//  537216 : s0g  f32[256]         (1024)
//  538240 : lse  f32              (4)

__device__ __forceinline__ float tanh_fast(float x) {
    // tanh(x) = 1 - 2/(exp(2x)+1); saturates correctly for large |x|
    float e = __expf(2.0f * x);
    return 1.0f - 2.0f / (e + 1.0f);
}

// ---------------------------------------------------------------- prep
__global__ __launch_bounds__(256) void k_prep(const float* __restrict__ Wm,
                                              const float* __restrict__ hc,
                                              const float* __restrict__ W1,
                                              __bf16* __restrict__ WmT,
                                              float* __restrict__ proj,
                                              float* __restrict__ s1g,
                                              float* __restrict__ s0g) {
    const int j = blockIdx.x;   // 0..255
    const int t = threadIdx.x;  // 0..255
    WmT[j * H_N + t] = (__bf16)Wm[t * H_N + j];   // B^T, k-contiguous
    __shared__ float red[H_N];
    red[t] = hc[t] * W1[j * H_N + t];
    __syncthreads();
    for (int off = 128; off > 0; off >>= 1) {
        if (t < off) red[t] += red[t + off];
        __syncthreads();
    }
    if (t == 0) proj[j] = red[0];
    if (j == 0) { s1g[t] = 0.0f; s0g[t] = 0.0f; }  // zero ct accumulators
}

// ---------------------------------------------------------------- fused At + LSE partials + ct partials
// 8 waves/block (512 thr); wave w owns cols [32w,32w+32) -> breg[8][2] = 64 VGPR
// (fits under the 128-reg cap of __launch_bounds__(512,4) => 4 waves/SIMD).
// 32-row tiles, double-buffered LDS, loads issued one full tile ahead.
__global__ __launch_bounds__(512, 4) void k_at(const float* __restrict__ Mt,
                                               const __bf16* __restrict__ WmT,
                                               const float* __restrict__ proj,
                                               const float* __restrict__ V,
                                               float* __restrict__ At,
                                               float2* __restrict__ part2,
                                               float* __restrict__ s1g,
                                               float* __restrict__ s0g) {
    const int tid = threadIdx.x;
    const int lane = tid & 63;
    const int w = tid >> 6;     // wave 0..7
    const int l15 = lane & 15;
    const int lg = lane >> 4;
    const int rg = tid >> 6;    // ct rows {rg, 8+rg, 16+rg, 24+rg}
    const int cg = tid & 63;    // ct cols 4cg..4cg+4

    __shared__ __align__(16) char sA[2][TM * 512];  // 2 x 16 KB bf16, XOR-swizzled
    __shared__ float part[8][TM];

    // ---- B resident in registers: col n = 32w+16fc+l15, k = 32ks+8lg
    bf16x8 breg[8][2];
#pragma unroll
    for (int ks = 0; ks < 8; ++ks)
#pragma unroll
        for (int fc = 0; fc < 2; ++fc)
            breg[ks][fc] = *(const bf16x8*)(WmT + (32 * w + 16 * fc + l15) * H_N + 32 * ks + 8 * lg);
    float pj[2], vj[2];
#pragma unroll
    for (int fc = 0; fc < 2; ++fc) {
        const int n = 32 * w + 16 * fc + l15;
        pj[fc] = proj[n];
        vj[fc] = V[n];
    }

    // staging: tile = 32 rows x 64 float4; idx = it*512+tid -> row=it*8+(tid>>6), kq=tid&63
    auto ld1 = [&](int tile, int it) -> float4 {
        if (tile < NT) {
            const int row = it * 8 + (tid >> 6);
            return *(const float4*)(Mt + (size_t)(tile * TM + row) * H_N + (tid & 63) * 4);
        }
        return make_float4(0.f, 0.f, 0.f, 0.f);
    };
    auto st1 = [&](int buf, int it, const float4& v) {
        const int row = it * 8 + (tid >> 6);
        const int kq = tid & 63;
        bf16x4 b;
        b[0] = (__bf16)v.x; b[1] = (__bf16)v.y; b[2] = (__bf16)v.z; b[3] = (__bf16)v.w;
        const int off = (row * 512 + kq * 8) ^ ((row & 7) << 4);
        *(bf16x4*)(&sA[buf][off]) = b;
    };

    float s1a[4] = {0.f, 0.f, 0.f, 0.f};
    float s0a[4] = {0.f, 0.f, 0.f, 0.f};
    float lm = -INFINITY, ls = 0.0f;

    int t = blockIdx.x;
    {
        float4 P[4];
#pragma unroll
        for (int it = 0; it < 4; ++it) P[it] = ld1(t, it);
#pragma unroll
        for (int it = 0; it < 4; ++it) st1(0, it, P[it]);
    }
    float4 S[4];
#pragma unroll
    for (int it = 0; it < 4; ++it) S[it] = ld1(t + GRID_AT, it);
    __syncthreads();

    int cur = 0;
    for (; t < NT; t += GRID_AT) {
        f32x4 acc[2][2];
#pragma unroll
        for (int m = 0; m < 2; ++m)
#pragma unroll
            for (int fc = 0; fc < 2; ++fc) {
                f32x4 z = {0.f, 0.f, 0.f, 0.f};
                acc[m][fc] = z;
            }

#pragma unroll
        for (int ph = 0; ph < 4; ++ph) {
#pragma unroll
            for (int kk = 0; kk < 2; ++kk) {
                const int ks = 2 * ph + kk;
                bf16x8 af[2];
#pragma unroll
                for (int m = 0; m < 2; ++m) {
                    const int r = 16 * m + l15;
                    const int off = (r * 512 + 64 * ks + 16 * lg) ^ ((r & 7) << 4);
                    af[m] = *(const bf16x8*)(&sA[cur][off]);
                }
#pragma unroll
                for (int m = 0; m < 2; ++m)
#pragma unroll
                    for (int fc = 0; fc < 2; ++fc)
                        acc[m][fc] = __builtin_amdgcn_mfma_f32_16x16x32_bf16(
                            af[m], breg[ks][fc], acc[m][fc], 0, 0, 0);
            }
            // consume staged quarter (issued one full tile ago), reissue for t+2G
            if (t + GRID_AT < NT) st1(cur ^ 1, ph, S[ph]);
            S[ph] = ld1(t + 2 * GRID_AT, ph);
        }

        // ---- epilogue: row partials over this wave's 32 cols
#pragma unroll
        for (int m = 0; m < 2; ++m)
#pragma unroll
            for (int i = 0; i < 4; ++i) {
                float p = tanh_fast(acc[m][0][i] + pj[0]) * vj[0]
                        + tanh_fast(acc[m][1][i] + pj[1]) * vj[1];
                p += __shfl_xor(p, 1);
                p += __shfl_xor(p, 2);
                p += __shfl_xor(p, 4);
                p += __shfl_xor(p, 8);
                if (l15 == 0) part[w][16 * m + 4 * lg + i] = p;
            }
        __syncthreads();  // A: part[] ready; sA[cur^1] fully staged; cur MFMA reads done

        if (tid < TM) {
            float at = 0.f;
#pragma unroll
            for (int g = 0; g < 8; ++g) at += part[g][tid];
            At[t * TM + tid] = at;
            if (at > lm) { ls = ls * __expf(lm - at) + 1.0f; lm = at; }
            else ls += __expf(at - lm);
        }
        // ---- ct partials from the bf16 tile still in LDS
#pragma unroll
        for (int j = 0; j < 4; ++j) {
            const int r = 8 * j + rg;
            float at_r = 0.f;
#pragma unroll
            for (int g = 0; g < 8; ++g) at_r += part[g][r];
            const int off = (r * 512 + 8 * cg) ^ ((r & 7) << 4);
            const bf16x4 vr = *(const bf16x4*)(&sA[cur][off]);
#pragma unroll
            for (int q = 0; q < 4; ++q) {
                const float x = (float)vr[q];
                s1a[q] += at_r * x;
                s0a[q] += x;
            }
        }
        __syncthreads();  // C: cur reads done before next tile's stage_writes hit it
        cur ^= 1;
    }

    // ---- block-level reduce of ct partials (reuse sA), then global atomics
    float* red1 = (float*)&sA[0][0];  // [8][256]
    float* red2 = (float*)&sA[1][0];
#pragma unroll
    for (int q = 0; q < 4; ++q) {
        red1[rg * 256 + 4 * cg + q] = s1a[q];
        red2[rg * 256 + 4 * cg + q] = s0a[q];
    }
    __syncthreads();
    if (tid < 256) {
        float a = 0.f;
#pragma unroll
        for (int g = 0; g < 8; ++g) a += red1[g * 256 + tid];
        atomicAdd(&s1g[tid], a);
    } else {
        const int c = tid - 256;
        float a = 0.f;
#pragma unroll
        for (int g = 0; g < 8; ++g) a += red2[g * 256 + c];
        atomicAdd(&s0g[c], a);
    }
    // ---- block LSE partial: tid<32 hold (lm,ls); reduce within wave 0
    if (w == 0) {
#pragma unroll
        for (int d = 1; d < 32; d <<= 1) {
            const float m2 = __shfl_xor(lm, d), s2 = __shfl_xor(ls, d);
            const float M = fmaxf(lm, m2);
            ls = ls * __expf(lm - M) + s2 * __expf(m2 - M);
            lm = M;
        }
        if (lane == 0) part2[blockIdx.x] = make_float2(lm, ls);
    }
}

// ---------------------------------------------------------------- final: LSE + ct
__global__ __launch_bounds__(512) void k_final(const float2* __restrict__ part2,
                                               const float* __restrict__ s1g,
                                               const float* __restrict__ s0g,
                                               float* __restrict__ lse,
                                               float* __restrict__ out) {
    const int tid = threadIdx.x;
    __shared__ float ms[512], ss[512];
    const float2 p = part2[tid];
    ms[tid] = p.x; ss[tid] = p.y;
    __syncthreads();
    for (int off = 256; off > 0; off >>= 1) {
        if (tid < off) {
            const float m2 = ms[tid + off], s2 = ss[tid + off];
            const float M = fmaxf(ms[tid], m2);
            ss[tid] = ss[tid] * __expf(ms[tid] - M) + s2 * __expf(m2 - M);
            ms[tid] = M;
        }
        __syncthreads();
    }
    __shared__ float Ls;
    if (tid == 0) { Ls = ms[0] + logf(ss[0]); *lse = Ls; }
    __syncthreads();
    if (tid < H_N) out[T_N + tid] = s1g[tid] - Ls * s0g[tid];
}

// ---------------------------------------------------------------- alphat = At - LSE
__global__ __launch_bounds__(256) void k_alpha(const float* __restrict__ At,
                                               const float* __restrict__ lse,
                                               float* __restrict__ out) {
    const float L = *lse;
    const int i4 = blockIdx.x * 256 + threadIdx.x;
    if (i4 < T_N / 4) {
        float4 a = *(const float4*)(At + i4 * 4);
        a.x -= L; a.y -= L; a.z -= L; a.w -= L;
        *(float4*)(out + i4 * 4) = a;
    }
}

// ----------------------------------------------------------------
extern "C" void kernel_launch(void* const* d_in, const int* in_sizes, int n_in,
                              void* d_out, int out_size, void* d_ws, size_t ws_size,
                              hipStream_t stream) {
    const float* inputs = (const float*)d_in[0];  // (T, H)
    const float* hc     = (const float*)d_in[1];  // (1, H)
    const float* Wm     = (const float*)d_in[2];  // (H, H)
    const float* V      = (const float*)d_in[3];  // (H, 1)
    const float* W1     = (const float*)d_in[4];  // (H, H)
    float* out = (float*)d_out;                   // [alphat (T) | ct (H)]

    char* ws = (char*)d_ws;
    __bf16* WmT  = (__bf16*)ws;
    float* proj  = (float*)(ws + 131072);
    float* At    = (float*)(ws + 132096);
    float2* p2   = (float2*)(ws + 532096);
    float* s1g   = (float*)(ws + 536192);
    float* s0g   = (float*)(ws + 537216);
    float* lse   = (float*)(ws + 538240);

    k_prep<<<256, 256, 0, stream>>>(Wm, hc, W1, WmT, proj, s1g, s0g);
    k_at<<<GRID_AT, 512, 0, stream>>>(inputs, WmT, proj, V, At, p2, s1g, s0g);
    k_final<<<1, 512, 0, stream>>>(p2, s1g, s0g, lse, out);
    k_alpha<<<98, 256, 0, stream>>>(At, lse, out);
}